// Round 10
// baseline (56.155 us; speedup 1.0000x reference)
//
#include <hip/hip_runtime.h>

// sites [4096,128] f32, consensus [512,128] f32
// out = softmax(-L1dist, axis=-1) -> [4096,512] f32
#define N_SITES 4096
#define M_CONS  512
#define DIM     128
#define RPB     8         // site rows per block
#define CH      32        // dims per chunk
#define NCH     4         // chunks (DIM/CH)

// Single fused kernel. Grid 512 blocks x 512 threads, LDS 64 KB ->
// 2 blocks/CU on 256 CUs = 16 waves/CU = 4 waves/SIMD.
// Polarity (validated in R9): lane owns consensus column col==tid; cv[CH] in
// VGPRs; site elements are block-uniform -> scalar loads -> SGPR operand;
// inner loop is pure VALU (v_sub+v_add with abs modifier).
// Per chunk (T14 async-stage split):
//   extract cv (8 x ds_read_b128, swizzled, structural-floor banks)
//   sync (LDS free) -> issue next chunk's 8 global float4 loads EARLY
//   compute 8 rows x 32 dims (hides the L2 latency of those loads)
//   ds_write staged regs -> sync (ready for next extract)
// Softmax: d stays in registers; dmat[8][512] overlay dump, wave wv reduces
// row wv (min + expsum via shuffles), broadcast red, coalesced store.
__global__ __launch_bounds__(512, 2) void fused_kernel(const float* __restrict__ sites,
                                                       const float* __restrict__ cons,
                                                       float* __restrict__ out) {
    __shared__ __align__(16) float lds[16384];   // 64 KB: consT chunk / dmat+red

    const int tid = threadIdx.x;
    const int bid = blockIdx.x;
    const int r0  = bid * RPB;

    // ---- prologue: stage chunk 0 directly (col r, quad q, swizzle q^(r&7))
#pragma unroll
    for (int it = 0; it < 8; it++) {
        int f = tid + it * 512;                  // 0..4095 quads
        int r = f >> 3, q = f & 7;
        float4 v = *(const float4*)(cons + (size_t)r * DIM + (q << 2));
        *(float4*)&lds[r * CH + ((q ^ (r & 7)) << 2)] = v;
    }
    __syncthreads();

    float d[RPB];
#pragma unroll
    for (int i = 0; i < RPB; i++) d[i] = 0.f;

    const float* srow = sites + (size_t)r0 * DIM;

#pragma unroll 1
    for (int h = 0; h < NCH; h++) {
        // ---- extract my column for chunk h (8-way spread = b128 floor)
        float cv[CH];
#pragma unroll
        for (int q = 0; q < 8; q++) {
            float4 v = *(const float4*)&lds[tid * CH + ((q ^ (tid & 7)) << 2)];
            cv[4*q+0] = v.x; cv[4*q+1] = v.y; cv[4*q+2] = v.z; cv[4*q+3] = v.w;
        }
        __syncthreads();                         // all extracts done; LDS reusable

        // ---- issue next chunk's global loads EARLY (hide under compute)
        float4 g[8];
        if (h < NCH - 1) {
#pragma unroll
            for (int it = 0; it < 8; it++) {
                int f = tid + it * 512;
                int r = f >> 3, q = f & 7;
                g[it] = *(const float4*)(cons + (size_t)r * DIM + (h + 1) * CH + (q << 2));
            }
        }

        // ---- pure-VALU accumulation: 8 rows x 32 dims (srow -> SGPR)
#pragma unroll
        for (int rr = 0; rr < RPB; rr++) {
#pragma unroll
            for (int k = 0; k < CH; k++)
                d[rr] += fabsf(srow[rr * DIM + h * CH + k] - cv[k]);
        }

        // ---- write staged regs to LDS for the next extract
        if (h < NCH - 1) {
#pragma unroll
            for (int it = 0; it < 8; it++) {
                int f = tid + it * 512;
                int r = f >> 3, q = f & 7;
                *(float4*)&lds[r * CH + ((q ^ (r & 7)) << 2)] = g[it];
            }
            __syncthreads();
        }
    }

    // ---- block-local softmax (block holds full 512-wide rows across lanes)
    // dmat[8][512] dump: consecutive lanes -> consecutive dwords (2-way, free)
#pragma unroll
    for (int rr = 0; rr < RPB; rr++)
        lds[rr * 512 + tid] = d[rr];
    __syncthreads();

    const int wv = tid >> 6;                     // wave wv reduces row wv
    const int ln = tid & 63;
    {
        const float* p = &lds[wv * 512 + ln * 8];
        float4 a = *(const float4*)(p);
        float4 b = *(const float4*)(p + 4);
        float m = fminf(fminf(fminf(a.x, a.y), fminf(a.z, a.w)),
                        fminf(fminf(b.x, b.y), fminf(b.z, b.w)));
#pragma unroll
        for (int off = 32; off > 0; off >>= 1) m = fminf(m, __shfl_xor(m, off));
        float s = ((__expf(m - a.x) + __expf(m - a.y)) + (__expf(m - a.z) + __expf(m - a.w)))
                + ((__expf(m - b.x) + __expf(m - b.y)) + (__expf(m - b.z) + __expf(m - b.w)));
#pragma unroll
        for (int off = 32; off > 0; off >>= 1) s += __shfl_xor(s, off);
        if (ln == 0) {
            lds[4096 + wv] = m;                  // row min
            lds[4104 + wv] = 1.f / s;            // row inv-sum (1 rcp per row)
        }
    }
    __syncthreads();

    // ---- final: exp(mn - d) * inv, coalesced 2 KB stores
#pragma unroll
    for (int rr = 0; rr < RPB; rr++) {
        float mn  = lds[4096 + rr];              // broadcast (same address)
        float inv = lds[4104 + rr];
        out[(size_t)(r0 + rr) * M_CONS + tid] = __expf(mn - d[rr]) * inv;
    }
}

extern "C" void kernel_launch(void* const* d_in, const int* in_sizes, int n_in,
                              void* d_out, int out_size, void* d_ws, size_t ws_size,
                              hipStream_t stream) {
    const float* sites = (const float*)d_in[0];
    const float* cons  = (const float*)d_in[1];
    float* out = (float*)d_out;

    fused_kernel<<<N_SITES / RPB, 512, 0, stream>>>(sites, cons, out);  // 512 blocks
}

// Round 11
// 28.564 us; speedup vs baseline: 1.9659x; 1.9659x over previous
//
#include <hip/hip_runtime.h>

// sites [4096,128] f32, consensus [512,128] f32
// out = softmax(-L1dist, axis=-1) -> [4096,512] f32
#define N_SITES 4096
#define M_CONS  512
#define DIM     128
#define RPB     16        // site rows per block
#define CH      32        // dims per chunk
#define NCH     4         // chunks
#define QPC     8         // quads per col per chunk (CH/4)

// Single fused kernel (R9 skeleton + global_load_lds double-buffer).
// 256 blocks x 512 threads, 128 KB LDS -> 1 block/CU.
// Lane owns consensus column col==tid (validated R9): cv[32] in VGPRs,
// site elements block-uniform -> s_load/SGPR operand -> inner loop pure VALU.
// Staging: chunk h+1 is DMA'd global->LDS via global_load_lds width=16 with
// PRE-SWIZZLED global source (slot f=(r,q) holds global quad q^(r&7) of col
// r); LDS dest stays linear (f*16B) as the instruction requires; the extract
// applies the same XOR -> reads spread over all 32 banks (col stride 128 B).
// No registers are consumed by staging, so the h+1 loads fly under chunk h's
// 2048-cycle compute and the end-of-chunk __syncthreads (vmcnt drain) is the
// only sync. Softmax: block-local as R9 (dmat overlay, wave-per-row reduce).
__global__ __launch_bounds__(512, 1) void fused_kernel(const float* __restrict__ sites,
                                                       const float* __restrict__ cons,
                                                       float* __restrict__ out) {
    __shared__ __align__(16) float lds[32768];   // 128 KB = 2 x 64 KB buffers

    const int tid = threadIdx.x;
    const int bid = blockIdx.x;
    const int r0  = bid * RPB;

    const int r_st = tid >> 3;                   // staging col  (slot f = c*512+tid)
    const int q_st = tid & 7;                    // staging quad slot

    // ---- prologue: DMA chunk 0 into buffer 0
#pragma unroll
    for (int c = 0; c < 8; c++) {
        const int f = c * 512 + tid;             // 0..4095 (64 KB / 16 B)
        const int r = f >> 3, q = f & 7;
        const float* gsrc = cons + (size_t)r * DIM + ((q ^ (r & 7)) << 2);
        __builtin_amdgcn_global_load_lds(
            (const __attribute__((address_space(1))) void*)gsrc,
            (__attribute__((address_space(3))) void*)&lds[f * 4], 16, 0, 0);
    }
    __syncthreads();

    float d[RPB];
#pragma unroll
    for (int i = 0; i < RPB; i++) d[i] = 0.f;

    const float* srow = sites + (size_t)r0 * DIM;

#pragma unroll
    for (int h = 0; h < NCH; h++) {
        float* cur = &lds[(h & 1) * 16384];      // compile-time (full unroll)
        float* nxt = &lds[((h + 1) & 1) * 16384];

        // ---- extract my column (8 x ds_read_b128, swizzled, conflict-free)
        float cv[CH];
#pragma unroll
        for (int q = 0; q < QPC; q++) {
            float4 v = *(const float4*)&cur[tid * CH + ((q ^ (tid & 7)) << 2)];
            cv[4*q+0] = v.x; cv[4*q+1] = v.y; cv[4*q+2] = v.z; cv[4*q+3] = v.w;
        }

        // ---- issue next chunk's DMA (zero register cost; lands under compute)
        if (h < NCH - 1) {
#pragma unroll
            for (int c = 0; c < 8; c++) {
                const int f = c * 512 + tid;
                const int r = f >> 3, q = f & 7;
                const float* gsrc = cons + (size_t)r * DIM + (h + 1) * CH
                                         + ((q ^ (r & 7)) << 2);
                __builtin_amdgcn_global_load_lds(
                    (const __attribute__((address_space(1))) void*)gsrc,
                    (__attribute__((address_space(3))) void*)&nxt[f * 4], 16, 0, 0);
            }
        }

        // ---- pure-VALU accumulation: 16 rows x 32 dims (srow -> SGPR)
#pragma unroll
        for (int rr = 0; rr < RPB; rr++) {
#pragma unroll
            for (int k = 0; k < CH; k++)
                d[rr] += fabsf(srow[rr * DIM + h * CH + k] - cv[k]);
        }

        __syncthreads();                         // drains vmcnt -> nxt ready
    }

    // ---- block-local softmax: dmat[16][512] overlay (32 KB of buffer 0)
#pragma unroll
    for (int rr = 0; rr < RPB; rr++)
        lds[rr * 512 + tid] = d[rr];             // consecutive lanes: 2-way, free
    __syncthreads();

    const int wv = tid >> 6;
    const int ln = tid & 63;
#pragma unroll
    for (int rep = 0; rep < 2; rep++) {          // wave wv reduces rows wv, wv+8
        int row = wv + rep * 8;
        const float* p = &lds[row * 512 + ln * 8];
        float4 a = *(const float4*)(p);
        float4 b = *(const float4*)(p + 4);
        float m = fminf(fminf(fminf(a.x, a.y), fminf(a.z, a.w)),
                        fminf(fminf(b.x, b.y), fminf(b.z, b.w)));
#pragma unroll
        for (int off = 32; off > 0; off >>= 1) m = fminf(m, __shfl_xor(m, off));
        float s = ((__expf(m - a.x) + __expf(m - a.y)) + (__expf(m - a.z) + __expf(m - a.w)))
                + ((__expf(m - b.x) + __expf(m - b.y)) + (__expf(m - b.z) + __expf(m - b.w)));
#pragma unroll
        for (int off = 32; off > 0; off >>= 1) s += __shfl_xor(s, off);
        if (ln == 0) {
            lds[8192 + row]      = m;            // row min
            lds[8192 + 16 + row] = 1.f / s;      // row inv-sum
        }
    }
    __syncthreads();

    // ---- final: exp(mn - d) * inv from registers, coalesced 2 KB stores
#pragma unroll
    for (int rr = 0; rr < RPB; rr++) {
        float mn  = lds[8192 + rr];              // broadcast (same address)
        float inv = lds[8192 + 16 + rr];
        out[(size_t)(r0 + rr) * M_CONS + tid] = __expf(mn - d[rr]) * inv;
    }
}

extern "C" void kernel_launch(void* const* d_in, const int* in_sizes, int n_in,
                              void* d_out, int out_size, void* d_ws, size_t ws_size,
                              hipStream_t stream) {
    const float* sites = (const float*)d_in[0];
    const float* cons  = (const float*)d_in[1];
    float* out = (float*)d_out;

    fused_kernel<<<N_SITES / RPB, 512, 0, stream>>>(sites, cons, out);  // 256 blocks
}

// Round 12
// 21.260 us; speedup vs baseline: 2.6413x; 1.3435x over previous
//
#include <hip/hip_runtime.h>

// sites [4096,128] f32, consensus [512,128] f32
// out = softmax(-L1dist, axis=-1) -> [4096,512] f32
#define N_SITES 4096
#define M_CONS  512
#define DIM     128
#define RPB     8         // site rows per block
#define CH      16        // dims per chunk
#define NCH     8         // chunks
#define QPC     4         // 16B-quads per col per chunk (CH/4)

// Single fused kernel (R11 skeleton at 2x occupancy).
// 512 blocks x 512 threads, 64 KB LDS (2 x 32 KB buffers) -> 2 blocks/CU
// = 16 waves/CU = 4 waves/SIMD; co-resident blocks overlap each other's
// barrier/staging phases.
// Lane owns consensus column col==tid (validated R9/R11): cv[CH] in VGPRs;
// site elements block-uniform -> scalar loads -> SGPR operand -> inner loop
// is pure VALU (v_sub + v_add with abs modifier).
// Staging: chunk h+1 DMA'd global->LDS (global_load_lds width=16) with
// PRE-SWIZZLED global source; LDS dest linear as required (#21).
// Swizzle key for CH=16 is ((r>>1)&3), NOT (r&3): slot s=4r+q holds global
// quad q^((r>>1)&3), so extract bank-start 4(c&1)+(g^((c>>1)&3)) covers all
// 8 residues evenly -> full 32-bank spread (the (r&3) key would leave 16
// banks idle at 64 B column stride).
// Softmax: block-local; dmat[8][512] overlay in buffer 0, wave wv reduces
// row wv (min + expsum via shuffles), broadcast red, coalesced stores.
__global__ __launch_bounds__(512, 1) void fused_kernel(const float* __restrict__ sites,
                                                       const float* __restrict__ cons,
                                                       float* __restrict__ out) {
    __shared__ __align__(16) float lds[16384];   // 64 KB = 2 x 32 KB buffers

    const int tid = threadIdx.x;
    const int bid = blockIdx.x;
    const int r0  = bid * RPB;

    // ---- prologue: DMA chunk 0 into buffer 0 (2048 slots, 4 per thread)
#pragma unroll
    for (int c = 0; c < 4; c++) {
        const int f = c * 512 + tid;             // slot 0..2047
        const int r = f >> 2, q = f & 3;
        const float* gsrc = cons + (size_t)r * DIM + ((q ^ ((r >> 1) & 3)) << 2);
        __builtin_amdgcn_global_load_lds(
            (const __attribute__((address_space(1))) void*)gsrc,
            (__attribute__((address_space(3))) void*)&lds[f * 4], 16, 0, 0);
    }
    __syncthreads();

    float d[RPB];
#pragma unroll
    for (int i = 0; i < RPB; i++) d[i] = 0.f;

    const float* srow = sites + (size_t)r0 * DIM;

#pragma unroll
    for (int h = 0; h < NCH; h++) {
        float* cur = &lds[(h & 1) * 8192];       // compile-time (full unroll)
        float* nxt = &lds[((h + 1) & 1) * 8192];

        // ---- extract my column (4 x ds_read_b128, full-bank spread)
        float cv[CH];
#pragma unroll
        for (int g = 0; g < QPC; g++) {
            float4 v = *(const float4*)&cur[tid * CH + ((g ^ ((tid >> 1) & 3)) << 2)];
            cv[4*g+0] = v.x; cv[4*g+1] = v.y; cv[4*g+2] = v.z; cv[4*g+3] = v.w;
        }

        // ---- issue next chunk's DMA (zero register cost, lands under compute)
        if (h < NCH - 1) {
#pragma unroll
            for (int c = 0; c < 4; c++) {
                const int f = c * 512 + tid;
                const int r = f >> 2, q = f & 3;
                const float* gsrc = cons + (size_t)r * DIM + (h + 1) * CH
                                         + ((q ^ ((r >> 1) & 3)) << 2);
                __builtin_amdgcn_global_load_lds(
                    (const __attribute__((address_space(1))) void*)gsrc,
                    (__attribute__((address_space(3))) void*)&nxt[f * 4], 16, 0, 0);
            }
        }

        // ---- pure-VALU accumulation: 8 rows x 16 dims (srow -> SGPR)
#pragma unroll
        for (int rr = 0; rr < RPB; rr++) {
#pragma unroll
            for (int k = 0; k < CH; k++)
                d[rr] += fabsf(srow[rr * DIM + h * CH + k] - cv[k]);
        }

        __syncthreads();                         // drains vmcnt -> nxt ready
    }

    // ---- block-local softmax: dmat[8][512] overlay (16 KB of buffer 0)
#pragma unroll
    for (int rr = 0; rr < RPB; rr++)
        lds[rr * 512 + tid] = d[rr];             // consecutive lanes: free
    __syncthreads();

    const int wv = tid >> 6;                     // wave wv reduces row wv
    const int ln = tid & 63;
    {
        const float* p = &lds[wv * 512 + ln * 8];
        float4 a = *(const float4*)(p);
        float4 b = *(const float4*)(p + 4);
        float m = fminf(fminf(fminf(a.x, a.y), fminf(a.z, a.w)),
                        fminf(fminf(b.x, b.y), fminf(b.z, b.w)));
#pragma unroll
        for (int off = 32; off > 0; off >>= 1) m = fminf(m, __shfl_xor(m, off));
        float s = ((__expf(m - a.x) + __expf(m - a.y)) + (__expf(m - a.z) + __expf(m - a.w)))
                + ((__expf(m - b.x) + __expf(m - b.y)) + (__expf(m - b.z) + __expf(m - b.w)));
#pragma unroll
        for (int off = 32; off > 0; off >>= 1) s += __shfl_xor(s, off);
        if (ln == 0) {
            lds[4096 + wv] = m;                  // row min
            lds[4104 + wv] = 1.f / s;            // row inv-sum
        }
    }
    __syncthreads();

    // ---- final: exp(mn - d) * inv from registers, coalesced 2 KB stores
#pragma unroll
    for (int rr = 0; rr < RPB; rr++) {
        float mn  = lds[4096 + rr];              // broadcast (same address)
        float inv = lds[4104 + rr];
        out[(size_t)(r0 + rr) * M_CONS + tid] = __expf(mn - d[rr]) * inv;
    }
}

extern "C" void kernel_launch(void* const* d_in, const int* in_sizes, int n_in,
                              void* d_out, int out_size, void* d_ws, size_t ws_size,
                              hipStream_t stream) {
    const float* sites = (const float*)d_in[0];
    const float* cons  = (const float*)d_in[1];
    float* out = (float*)d_out;

    fused_kernel<<<N_SITES / RPB, 512, 0, stream>>>(sites, cons, out);  // 512 blocks
}